// Round 6
// baseline (500.906 us; speedup 1.0000x reference)
//
#include <hip/hip_runtime.h>

#define NSPL 191                 // 3*64 - 1 spline dims
constexpr float MIN_W = 0.001f, MIN_H = 0.001f, MIN_D = 0.001f;
constexpr float W_A = -10000.0f, AB = 20000.0f;
constexpr float LOG_HALF = -0.69314718055994530942f;
constexpr float LOG_AB   = 9.90348755253612804622f;   // ln(20000)

// 4-float vectors: unaligned (row bases are 4B-aligned only) and 16B (LDS)
typedef float f4  __attribute__((ext_vector_type(4), aligned(4)));
typedef float f4a __attribute__((ext_vector_type(4), aligned(16)));

// DPP add within 16-lane rows; bound_ctrl=1 -> shifted-in lanes contribute 0
template<int CTRL>
__device__ __forceinline__ float dpp_add(float x) {
    int t = __builtin_amdgcn_update_dpp(0, __float_as_int(x), CTRL, 0xf, 0xf, true);
    return x + __int_as_float(t);
}
template<int PAT>
__device__ __forceinline__ float swz_f(float x) {
    return __int_as_float(__builtin_amdgcn_ds_swizzle(__float_as_int(x), PAT));
}
template<int PAT>
__device__ __forceinline__ int swz_i(int x) {
    return __builtin_amdgcn_ds_swizzle(x, PAT);
}

// One cut's full pipeline for a 16-lane group (lane sub owns bins 4sub..4sub+3).
// gl = this cut's private 192-float LDS slab: [0..63]=h-cumsum, [64..127]=ew,
// [128..191]=raw padded-ud u. Same-wave DS ordering -> no barrier needed.
__device__ __forceinline__ float cut_logdet(
    const f4 dw, const f4 dh, const f4 du,
    const f4 ww, const f4 wh, const f4 wu,
    float x, float* __restrict__ gl, int sub)
{
    const int cb = 4 * sub;

    // raw ud (no softplus) -> slab
    *(f4a*)(gl + 128 + cb) = (f4a){du.x + wu.x, du.y + wu.y, du.z + wu.z, du.w + wu.w};

    // exp (no max-subtract; inputs ~0.54 +/- 0.3)
    const float ew0 = __expf(dw.x + ww.x), ew1 = __expf(dw.y + ww.y);
    const float ew2 = __expf(dw.z + ww.z), ew3 = __expf(dw.w + ww.w);
    const float eh0 = __expf(dh.x + wh.x), eh1 = __expf(dh.y + wh.y);
    const float eh2 = __expf(dh.z + wh.z), eh3 = __expf(dh.w + wh.w);

    *(f4a*)(gl + 64 + cb) = (f4a){ew0, ew1, ew2, ew3};

    // Sw: 16-lane xor-butterfly (xor 1,2,4,8)
    float Sw = (ew0 + ew1) + (ew2 + ew3);
    Sw += swz_f<0x041F>(Sw); Sw += swz_f<0x081F>(Sw);
    Sw += swz_f<0x101F>(Sw); Sw += swz_f<0x201F>(Sw);

    // h: 64-point inclusive cumsum (4 regs x 16 lanes via DPP row scan)
    float c0 = eh0, c1 = c0 + eh1, c2 = c1 + eh2, c3 = c2 + eh3;
    float t = c3;
    t = dpp_add<0x111>(t);   // row_shr:1
    t = dpp_add<0x112>(t);   // row_shr:2
    t = dpp_add<0x114>(t);   // row_shr:4
    t = dpp_add<0x118>(t);   // row_shr:8
    const float base = t - c3;
    c0 += base; c1 += base; c2 += base; c3 += base;

    *(f4a*)(gl + cb) = (f4a){c0, c1, c2, c3};

    const float Sh = swz_f<0x1F0>(c3);     // broadcast lane 15 (group total)

    const float wsc2 = __fdividef(2.0f * (1.0f - 64.0f * MIN_W), Sw);
    const float hsc2 = __fdividef(2.0f * (1.0f - 64.0f * MIN_H), Sh);

    // bin index: count interior right-edges <= x
    const float off2 = 2.0f * MIN_H;
    const float p1 = (float)(cb + 1);
    const float e0v = fmaf(hsc2, c0, fmaf(off2, p1,        -1.0f));
    const float e1v = fmaf(hsc2, c1, fmaf(off2, p1 + 1.0f, -1.0f));
    const float e2v = fmaf(hsc2, c2, fmaf(off2, p1 + 2.0f, -1.0f));
    float       e3v = fmaf(hsc2, c3, fmaf(off2, p1 + 3.0f, -1.0f));
    if (sub == 15) e3v = 2.0f;             // edge 63 is 1+1e-6: never taken
    int cnt = (x >= e0v) + (x >= e1v) + (x >= e2v) + (x >= e3v);
    cnt += swz_i<0x041F>(cnt); cnt += swz_i<0x081F>(cnt);
    cnt += swz_i<0x101F>(cnt); cnt += swz_i<0x201F>(cnt);
    const int idx = cnt;                   // group-uniform, 0..63

    // epilogue gathers from slab (broadcast ds_read_b32)
    const float capEh_r = gl[(idx > 0) ? (idx - 1) : 0];
    const float capEh   = (idx == 0) ? 0.0f : capEh_r;
    const float C_idx   = gl[idx];
    const float eh_i    = C_idx - capEh;
    const float ew_i    = gl[64 + idx];
    const float u_d0    = gl[128 + idx];               // used when idx>=1
    const float u_d1    = gl[128 + ((idx + 1) & 63)];  // used when idx<=62
    const float d0 = (idx == 0)  ? 1.0f : (MIN_D + __logf(1.0f + __expf(u_d0)));
    const float d1 = (idx == 63) ? 1.0f : (MIN_D + __logf(1.0f + __expf(u_d1)));

    // RQS inverse logdet
    const float in_w = fmaf(wsc2, ew_i, 2.0f * MIN_W);
    const float in_h = fmaf(hsc2, eh_i, 2.0f * MIN_H);
    const float ch_l = fmaf(hsc2, capEh, fmaf(off2, (float)idx, -1.0f));

    const float delta = __fdividef(in_h, in_w);
    const float dy = x - ch_l;
    const float ss = d0 + d1 - 2.0f * delta;
    const float aa = dy * ss + in_h * (delta - d0);
    const float bb = in_h * d0 - dy * ss;
    const float cc = -delta * dy;
    const float disc = bb * bb - 4.0f * aa * cc;
    const float root = __fdividef(2.0f * cc, -bb - sqrtf(fmaxf(disc, 0.0f)));
    const float tom = root * (1.0f - root);
    const float denom = delta + ss * tom;
    const float omr = 1.0f - root;
    const float dnum = delta * delta * (d1 * root * root + 2.0f * delta * tom + d0 * omr * omr);
    return -(__logf(dnum) - 2.0f * __logf(denom));
}

// 16 lanes per group, TWO cuts per group (i and i+16): all 12 global quad
// loads issued up-front -> 2x bytes in flight + 2 independent chains per wave.
__global__ __launch_bounds__(256, 4) void rqs_g16x2_kernel(
    const float* __restrict__ value,
    const float* __restrict__ dsg,       // delta_spline [n,191]
    const int*   __restrict__ genes_oi,
    const int*   __restrict__ lgi,
    const float* __restrict__ swg,       // spline_weight [5000,191]
    float* __restrict__ out, int n)
{
    __shared__ float lds[32 * 192];      // 32 cut-slabs (24 KB)

    const int sub = threadIdx.x & 15;
    const int gid = threadIdx.x >> 4;                 // 0..15
    const long base = (long)blockIdx.x * 32;
    const long iA = base + gid, iB = base + gid + 16;
    const int icA = (int)(iA < (long)n ? iA : (long)(n - 1));
    const int icB = (int)(iB < (long)n ? iB : (long)(n - 1));

    const int gA = genes_oi[lgi[icA]];
    const int gB = genes_oi[lgi[icB]];
    const float vA = value[icA];
    const float vB = value[icB];

    const float* __restrict__ dsrA = dsg + (long)icA * NSPL;
    const float* __restrict__ dsrB = dsg + (long)icB * NSPL;
    const float* __restrict__ swrA = swg + (long)gA  * NSPL;
    const float* __restrict__ swrB = swg + (long)gB  * NSPL;

    const int cb = 4 * sub;
    // all 12 quad loads up-front (independent; compiler clusters them)
    const f4 dwA = *(const f4*)(dsrA + cb);
    const f4 dhA = *(const f4*)(dsrA + 64 + cb);
    const f4 duA = *(const f4*)(dsrA + 127 + cb);
    const f4 dwB = *(const f4*)(dsrB + cb);
    const f4 dhB = *(const f4*)(dsrB + 64 + cb);
    const f4 duB = *(const f4*)(dsrB + 127 + cb);
    const f4 wwA = *(const f4*)(swrA + cb);
    const f4 whA = *(const f4*)(swrA + 64 + cb);
    const f4 wuA = *(const f4*)(swrA + 127 + cb);
    const f4 wwB = *(const f4*)(swrB + cb);
    const f4 whB = *(const f4*)(swrB + 64 + cb);
    const f4 wuB = *(const f4*)(swrB + 127 + cb);

    float xA = fmaf(vA - W_A, 2.0f / AB, -1.0f);
    const bool insA = (xA >= -1.0f) && (xA <= 1.0f);
    xA = fminf(fmaxf(xA, -1.0f), 1.0f);
    float xB = fmaf(vB - W_A, 2.0f / AB, -1.0f);
    const bool insB = (xB >= -1.0f) && (xB <= 1.0f);
    xB = fminf(fmaxf(xB, -1.0f), 1.0f);

    const float ldA = cut_logdet(dwA, dhA, duA, wwA, whA, wuA, xA,
                                 lds + gid * 192, sub);
    const float ldB = cut_logdet(dwB, dhB, duB, wwB, whB, wuB, xB,
                                 lds + (16 + gid) * 192, sub);

    if (sub == 0) {
        if (iA < (long)n) out[iA] = LOG_HALF + (insA ? ldA : 0.0f) - LOG_AB;
        if (iB < (long)n) out[iB] = LOG_HALF + (insB ? ldB : 0.0f) - LOG_AB;
    }
}

extern "C" void kernel_launch(void* const* d_in, const int* in_sizes, int n_in,
                              void* d_out, int out_size, void* d_ws, size_t ws_size,
                              hipStream_t stream) {
    const float* value         = (const float*)d_in[0];
    const float* delta_spline  = (const float*)d_in[1];
    const int*   genes_oi      = (const int*)d_in[2];
    const int*   local_gene_ix = (const int*)d_in[3];
    const float* spline_weight = (const float*)d_in[4];
    float* out = (float*)d_out;

    const int n = in_sizes[0];
    const int cuts_per_block = 32;          // 4 waves x 4 groups x 2 cuts
    const int blocks = (n + cuts_per_block - 1) / cuts_per_block;
    rqs_g16x2_kernel<<<blocks, 256, 0, stream>>>(
        value, delta_spline, genes_oi, local_gene_ix, spline_weight, out, n);
}